// Round 1
// baseline (723.489 us; speedup 1.0000x reference)
//
#include <hip/hip_runtime.h>
#include <hip/hip_bf16.h>

#define N_NODES 10000
#define N_EDGES 320000
#define D 128
#define H 512

typedef __bf16 bf16x8 __attribute__((ext_vector_type(8)));
typedef float f32x4 __attribute__((ext_vector_type(4)));
typedef unsigned short u16x8 __attribute__((ext_vector_type(8)));

__device__ __forceinline__ unsigned short f2bf(float f) {
    union { float f; unsigned u; } v; v.f = f;
    unsigned r = v.u + 0x7fffu + ((v.u >> 16) & 1u);
    return (unsigned short)(r >> 16);
}

// ---------------- precompute: cast x to bf16 ----------------
__global__ void cast_x_kernel(const float* __restrict__ x, unsigned short* __restrict__ xb) {
    int t = blockIdx.x * 256 + threadIdx.x;        // exactly N_NODES*D/4 threads
    float4 v = reinterpret_cast<const float4*>(x)[t];
    ushort4 o;
    o.x = f2bf(v.x); o.y = f2bf(v.y); o.z = f2bf(v.z); o.w = f2bf(v.w);
    reinterpret_cast<ushort4*>(xb)[t] = o;
}

// ---------------- precompute: swizzle weight [K][N] fp32 -> MFMA-B-frag layout bf16 ----
// out layout: [(kt*(N/16)+nt)*64 + lane] * 8 bf16, element j = W[kt*32+(lane>>4)*8+j][nt*16+(lane&15)]
__global__ void swizzle_w_kernel(const float* __restrict__ W, unsigned short* __restrict__ out,
                                 int K, int Nn) {
    int t = blockIdx.x * 256 + threadIdx.x;
    int total = (K >> 5) * (Nn >> 4) * 64;
    if (t >= total) return;
    int lane = t & 63;
    int tile = t >> 6;
    int ntiles = Nn >> 4;
    int nt = tile % ntiles;
    int kt = tile / ntiles;
    int k0 = kt * 32 + (lane >> 4) * 8;
    int n  = nt * 16 + (lane & 15);
    unsigned short tmp[8];
#pragma unroll
    for (int j = 0; j < 8; ++j) tmp[j] = f2bf(W[(size_t)(k0 + j) * Nn + n]);
    ushort4* dst = reinterpret_cast<ushort4*>(out + (size_t)t * 8);
    dst[0] = *reinterpret_cast<ushort4*>(&tmp[0]);
    dst[1] = *reinterpret_cast<ushort4*>(&tmp[4]);
}

// ---------------- fused edge MLP + scatter ----------------
// block = 256 thr (4 waves), tile = 64 edges.
// GEMM1: [64,384] @ We1[384,512]   (wave w owns n-tiles {h*8+w*2, h*8+w*2+1} per chunk h)
// GEMM2: hidden [64,512] @ We2[512,128]  (wave w owns out n-tiles {w*2, w*2+1})
__global__ __launch_bounds__(256) void edge_mlp_kernel(
    const unsigned short* __restrict__ xb,
    const int* __restrict__ eidx,
    const float* __restrict__ edge_attr,
    const unsigned short* __restrict__ We1s,
    const float* __restrict__ be1,
    const unsigned short* __restrict__ We2s,
    const float* __restrict__ be2,
    float* __restrict__ out_edges,
    float* __restrict__ agg)
{
    __shared__ unsigned short sA[64 * 392];   // [64][384+8] bf16
    __shared__ unsigned short sH[64 * 136];   // [64][128+8] bf16 hidden chunk

    const int tid = threadIdx.x;
    const int wave = tid >> 6, lane = tid & 63;
    const int e0 = blockIdx.x * 64;
    const int l15 = lane & 15;
    const int q8 = (lane >> 4) * 8;

    // ---- stage A: concat(x[s], x[r], edge_attr) as bf16 ----
#pragma unroll
    for (int seg = 0; seg < 2; ++seg) {
        for (int c = tid; c < 1024; c += 256) {
            int row = c >> 4;
            int off = (c & 15) << 3;
            int e = e0 + row;
            int node = eidx[seg * N_EDGES + e];
            *reinterpret_cast<bf16x8*>(&sA[row * 392 + seg * 128 + off]) =
                *reinterpret_cast<const bf16x8*>(&xb[(size_t)node * 128 + off]);
        }
    }
    for (int c = tid; c < 1024; c += 256) {
        int row = c >> 4;
        int off = (c & 15) << 3;
        int e = e0 + row;
        const float4* src = reinterpret_cast<const float4*>(&edge_attr[(size_t)e * 128 + off]);
        float4 v0 = src[0], v1 = src[1];
        u16x8 o;
        o[0] = f2bf(v0.x); o[1] = f2bf(v0.y); o[2] = f2bf(v0.z); o[3] = f2bf(v0.w);
        o[4] = f2bf(v1.x); o[5] = f2bf(v1.y); o[6] = f2bf(v1.z); o[7] = f2bf(v1.w);
        *reinterpret_cast<u16x8*>(&sA[row * 392 + 256 + off]) = o;
    }
    __syncthreads();

    f32x4 acc2[2][4];
#pragma unroll
    for (int nn = 0; nn < 2; ++nn)
#pragma unroll
        for (int mt = 0; mt < 4; ++mt) acc2[nn][mt] = (f32x4){0.f, 0.f, 0.f, 0.f};

#pragma unroll 1
    for (int h = 0; h < 4; ++h) {
        f32x4 acc1[2][4];
#pragma unroll
        for (int nn = 0; nn < 2; ++nn)
#pragma unroll
            for (int mt = 0; mt < 4; ++mt) acc1[nn][mt] = (f32x4){0.f, 0.f, 0.f, 0.f};

#pragma unroll
        for (int kt = 0; kt < 12; ++kt) {
            bf16x8 a[4];
#pragma unroll
            for (int mt = 0; mt < 4; ++mt)
                a[mt] = *reinterpret_cast<const bf16x8*>(&sA[(mt * 16 + l15) * 392 + kt * 32 + q8]);
#pragma unroll
            for (int nn = 0; nn < 2; ++nn) {
                int ntile = h * 8 + wave * 2 + nn;   // global n-tile 0..31
                bf16x8 b = *reinterpret_cast<const bf16x8*>(
                    &We1s[(((size_t)kt * 32 + ntile) * 64 + lane) * 8]);
#pragma unroll
                for (int mt = 0; mt < 4; ++mt)
                    acc1[nn][mt] = __builtin_amdgcn_mfma_f32_16x16x32_bf16(a[mt], b, acc1[nn][mt], 0, 0, 0);
            }
        }

        // hidden = relu(acc1 + be1) -> bf16 -> sH (C-layout -> A-layout via LDS)
        __syncthreads();   // previous chunk's GEMM2 reads of sH are done
#pragma unroll
        for (int nn = 0; nn < 2; ++nn) {
            int cc = (wave * 2 + nn) * 16 + l15;     // col within 128-chunk
            float bias = be1[h * 128 + cc];
#pragma unroll
            for (int mt = 0; mt < 4; ++mt)
#pragma unroll
                for (int r = 0; r < 4; ++r) {
                    float v = acc1[nn][mt][r] + bias;
                    v = v > 0.f ? v : 0.f;
                    int row = mt * 16 + (lane >> 4) * 4 + r;
                    sH[row * 136 + cc] = f2bf(v);
                }
        }
        __syncthreads();

        // GEMM2 partial over this hidden chunk
#pragma unroll
        for (int kt = 0; kt < 4; ++kt) {
            bf16x8 a[4];
#pragma unroll
            for (int mt = 0; mt < 4; ++mt)
                a[mt] = *reinterpret_cast<const bf16x8*>(&sH[(mt * 16 + l15) * 136 + kt * 32 + q8]);
#pragma unroll
            for (int nn = 0; nn < 2; ++nn) {
                int ntile = wave * 2 + nn;           // 0..7 over D=128
                bf16x8 b = *reinterpret_cast<const bf16x8*>(
                    &We2s[(((size_t)(h * 4 + kt) * 8 + ntile) * 64 + lane) * 8]);
#pragma unroll
                for (int mt = 0; mt < 4; ++mt)
                    acc2[nn][mt] = __builtin_amdgcn_mfma_f32_16x16x32_bf16(a[mt], b, acc2[nn][mt], 0, 0, 0);
            }
        }
    }

    // ---- epilogue: write updated_edge_attr + atomic scatter into agg ----
#pragma unroll
    for (int nn = 0; nn < 2; ++nn) {
        int cc = (wave * 2 + nn) * 16 + l15;
        float bias = be2[cc];
#pragma unroll
        for (int mt = 0; mt < 4; ++mt)
#pragma unroll
            for (int r = 0; r < 4; ++r) {
                int row = mt * 16 + (lane >> 4) * 4 + r;
                int e = e0 + row;
                float v = acc2[nn][mt][r] + bias;
                out_edges[(size_t)e * 128 + cc] = v;
                int recv = eidx[N_EDGES + e];
                atomicAdd(&agg[(size_t)recv * 128 + cc], v);
            }
    }
}

// ---------------- fused node MLP ----------------
__global__ __launch_bounds__(256) void node_mlp_kernel(
    const unsigned short* __restrict__ xb,
    const float* __restrict__ agg,
    const unsigned short* __restrict__ Wn1s,
    const float* __restrict__ bn1,
    const unsigned short* __restrict__ Wn2s,
    const float* __restrict__ bn2,
    float* __restrict__ out_nodes)
{
    __shared__ unsigned short sA[64 * 264];   // [64][256+8] bf16
    __shared__ unsigned short sH[64 * 136];

    const int tid = threadIdx.x;
    const int wave = tid >> 6, lane = tid & 63;
    const int n0 = blockIdx.x * 64;
    const int l15 = lane & 15;
    const int q8 = (lane >> 4) * 8;

    // stage A = concat(x_bf16, bf16(agg))
    for (int c = tid; c < 1024; c += 256) {
        int row = c >> 4;
        int off = (c & 15) << 3;
        int node = n0 + row;
        bf16x8 v = {};
        if (node < N_NODES)
            v = *reinterpret_cast<const bf16x8*>(&xb[(size_t)node * 128 + off]);
        *reinterpret_cast<bf16x8*>(&sA[row * 264 + off]) = v;
    }
    for (int c = tid; c < 1024; c += 256) {
        int row = c >> 4;
        int off = (c & 15) << 3;
        int node = n0 + row;
        u16x8 o = {0, 0, 0, 0, 0, 0, 0, 0};
        if (node < N_NODES) {
            const float4* src = reinterpret_cast<const float4*>(&agg[(size_t)node * 128 + off]);
            float4 v0 = src[0], v1 = src[1];
            o[0] = f2bf(v0.x); o[1] = f2bf(v0.y); o[2] = f2bf(v0.z); o[3] = f2bf(v0.w);
            o[4] = f2bf(v1.x); o[5] = f2bf(v1.y); o[6] = f2bf(v1.z); o[7] = f2bf(v1.w);
        }
        *reinterpret_cast<u16x8*>(&sA[row * 264 + 128 + off]) = o;
    }
    __syncthreads();

    f32x4 acc2[2][4];
#pragma unroll
    for (int nn = 0; nn < 2; ++nn)
#pragma unroll
        for (int mt = 0; mt < 4; ++mt) acc2[nn][mt] = (f32x4){0.f, 0.f, 0.f, 0.f};

#pragma unroll 1
    for (int h = 0; h < 4; ++h) {
        f32x4 acc1[2][4];
#pragma unroll
        for (int nn = 0; nn < 2; ++nn)
#pragma unroll
            for (int mt = 0; mt < 4; ++mt) acc1[nn][mt] = (f32x4){0.f, 0.f, 0.f, 0.f};

#pragma unroll
        for (int kt = 0; kt < 8; ++kt) {       // K = 256
            bf16x8 a[4];
#pragma unroll
            for (int mt = 0; mt < 4; ++mt)
                a[mt] = *reinterpret_cast<const bf16x8*>(&sA[(mt * 16 + l15) * 264 + kt * 32 + q8]);
#pragma unroll
            for (int nn = 0; nn < 2; ++nn) {
                int ntile = h * 8 + wave * 2 + nn;
                bf16x8 b = *reinterpret_cast<const bf16x8*>(
                    &Wn1s[(((size_t)kt * 32 + ntile) * 64 + lane) * 8]);
#pragma unroll
                for (int mt = 0; mt < 4; ++mt)
                    acc1[nn][mt] = __builtin_amdgcn_mfma_f32_16x16x32_bf16(a[mt], b, acc1[nn][mt], 0, 0, 0);
            }
        }

        __syncthreads();
#pragma unroll
        for (int nn = 0; nn < 2; ++nn) {
            int cc = (wave * 2 + nn) * 16 + l15;
            float bias = bn1[h * 128 + cc];
#pragma unroll
            for (int mt = 0; mt < 4; ++mt)
#pragma unroll
                for (int r = 0; r < 4; ++r) {
                    float v = acc1[nn][mt][r] + bias;
                    v = v > 0.f ? v : 0.f;
                    int row = mt * 16 + (lane >> 4) * 4 + r;
                    sH[row * 136 + cc] = f2bf(v);
                }
        }
        __syncthreads();

#pragma unroll
        for (int kt = 0; kt < 4; ++kt) {
            bf16x8 a[4];
#pragma unroll
            for (int mt = 0; mt < 4; ++mt)
                a[mt] = *reinterpret_cast<const bf16x8*>(&sH[(mt * 16 + l15) * 136 + kt * 32 + q8]);
#pragma unroll
            for (int nn = 0; nn < 2; ++nn) {
                int ntile = wave * 2 + nn;
                bf16x8 b = *reinterpret_cast<const bf16x8*>(
                    &Wn2s[(((size_t)(h * 4 + kt) * 8 + ntile) * 64 + lane) * 8]);
#pragma unroll
                for (int mt = 0; mt < 4; ++mt)
                    acc2[nn][mt] = __builtin_amdgcn_mfma_f32_16x16x32_bf16(a[mt], b, acc2[nn][mt], 0, 0, 0);
            }
        }
    }

#pragma unroll
    for (int nn = 0; nn < 2; ++nn) {
        int cc = (wave * 2 + nn) * 16 + l15;
        float bias = bn2[cc];
#pragma unroll
        for (int mt = 0; mt < 4; ++mt)
#pragma unroll
            for (int r = 0; r < 4; ++r) {
                int row = mt * 16 + (lane >> 4) * 4 + r;
                int node = n0 + row;
                if (node < N_NODES)
                    out_nodes[(size_t)node * 128 + cc] = acc2[nn][mt][r] + bias;
            }
    }
}

extern "C" void kernel_launch(void* const* d_in, const int* in_sizes, int n_in,
                              void* d_out, int out_size, void* d_ws, size_t ws_size,
                              hipStream_t stream) {
    const float* x         = (const float*)d_in[0];
    const int*   eidx      = (const int*)d_in[1];
    const float* edge_attr = (const float*)d_in[2];
    const float* We1       = (const float*)d_in[3];
    const float* be1       = (const float*)d_in[4];
    const float* We2       = (const float*)d_in[5];
    const float* be2       = (const float*)d_in[6];
    const float* Wn1       = (const float*)d_in[7];
    const float* bn1       = (const float*)d_in[8];
    const float* Wn2       = (const float*)d_in[9];
    const float* bn2       = (const float*)d_in[10];
    float* out = (float*)d_out;

    char* ws = (char*)d_ws;
    size_t off = 0;
    auto alloc = [&](size_t bytes) {
        void* p = ws + off;
        off += (bytes + 255) & ~(size_t)255;
        return p;
    };
    unsigned short* xb   = (unsigned short*)alloc((size_t)N_NODES * D * 2);
    unsigned short* We1s = (unsigned short*)alloc((size_t)384 * 512 * 2);
    unsigned short* We2s = (unsigned short*)alloc((size_t)512 * 128 * 2);
    unsigned short* Wn1s = (unsigned short*)alloc((size_t)256 * 512 * 2);
    unsigned short* Wn2s = (unsigned short*)alloc((size_t)512 * 128 * 2);
    float*          agg  = (float*)alloc((size_t)N_NODES * D * 4);

    hipMemsetAsync(agg, 0, (size_t)N_NODES * D * sizeof(float), stream);
    cast_x_kernel<<<(N_NODES * D / 4 + 255) / 256, 256, 0, stream>>>(x, xb);
    swizzle_w_kernel<<<(12 * 32 * 64 + 255) / 256, 256, 0, stream>>>(We1, We1s, 384, 512);
    swizzle_w_kernel<<<(16 * 8 * 64 + 255) / 256, 256, 0, stream>>>(We2, We2s, 512, 128);
    swizzle_w_kernel<<<(8 * 32 * 64 + 255) / 256, 256, 0, stream>>>(Wn1, Wn1s, 256, 512);
    swizzle_w_kernel<<<(16 * 8 * 64 + 255) / 256, 256, 0, stream>>>(Wn2, Wn2s, 512, 128);

    edge_mlp_kernel<<<N_EDGES / 64, 256, 0, stream>>>(
        xb, eidx, edge_attr, We1s, be1, We2s, be2, out + (size_t)N_NODES * D, agg);
    node_mlp_kernel<<<(N_NODES + 63) / 64, 256, 0, stream>>>(
        xb, agg, Wn1s, bn1, Wn2s, bn2, out);
}